// Round 2
// baseline (684.358 us; speedup 1.0000x reference)
//
#include <hip/hip_runtime.h>
#include <hip/hip_fp16.h>

#define T_STEPS 2048
#define BATCH 16
#define DIMD 1024
#define NSTATE 1024
#define MROWS (T_STEPS * BATCH)   // 32768
#define NCH (BATCH * NSTATE)      // 16384

typedef _Float16 f16x8 __attribute__((ext_vector_type(8)));
typedef float f32x4 __attribute__((ext_vector_type(4)));

#define GAS(p) ((const __attribute__((address_space(1))) void*)(p))
#define LAS(p) ((__attribute__((address_space(3))) void*)(p))

// ---------------- f32 -> f16 convert, 8 elements/thread ----------------
__global__ void cvt_kernel(const float* __restrict__ src, _Float16* __restrict__ dst, int n8) {
  int i = blockIdx.x * blockDim.x + threadIdx.x;
  if (i >= n8) return;
  const float4* s4 = (const float4*)src;
  float4 a = s4[(size_t)i * 2];
  float4 b = s4[(size_t)i * 2 + 1];
  f16x8 o;
  o[0] = (_Float16)a.x; o[1] = (_Float16)a.y; o[2] = (_Float16)a.z; o[3] = (_Float16)a.w;
  o[4] = (_Float16)b.x; o[5] = (_Float16)b.y; o[6] = (_Float16)b.z; o[7] = (_Float16)b.w;
  *((f16x8*)dst + i) = o;
}

// ---------------- GEMM: C[m][n] = sum_d A[m][d] * W[n][d]  (NT layout), f16 out ----
__global__ void gemm_kernel(const _Float16* __restrict__ A,
                            const _Float16* __restrict__ Wcat,
                            _Float16* __restrict__ Cout) {
  __shared__ _Float16 As[128 * 32];
  __shared__ _Float16 Bs[128 * 32];
  const int tid = threadIdx.x;
  const int lane = tid & 63;
  const int wid = tid >> 6;
  const int wm = wid >> 1;   // 0..1
  const int wn = wid & 1;    // 0..1
  const int tileN = blockIdx.x;   // 0..7
  const int tileM = blockIdx.y;   // 0..255
  const int mat = blockIdx.z;     // 0..2  (k, v, q)

  const _Float16* Ag = A + (size_t)tileM * 128 * DIMD;
  const _Float16* Bg = Wcat + (size_t)mat * NSTATE * DIMD + (size_t)tileN * 128 * DIMD;
  _Float16* C = Cout + (size_t)mat * MROWS * NSTATE;

  f32x4 acc[4][4];
#pragma unroll
  for (int m = 0; m < 4; ++m)
#pragma unroll
    for (int n = 0; n < 4; ++n)
      acc[m][n] = (f32x4){0.f, 0.f, 0.f, 0.f};

  const int srow = tid >> 2;         // 0..63
  const int scolh = (tid & 3) * 8;   // offset within BK=32

  for (int kt = 0; kt < DIMD; kt += 32) {
#pragma unroll
    for (int i = 0; i < 2; ++i) {
      __builtin_amdgcn_global_load_lds(GAS(Ag + (size_t)(srow + i * 64) * DIMD + kt + scolh),
                                       LAS(As + (i * 256 + tid) * 8), 16, 0, 0);
      __builtin_amdgcn_global_load_lds(GAS(Bg + (size_t)(srow + i * 64) * DIMD + kt + scolh),
                                       LAS(Bs + (i * 256 + tid) * 8), 16, 0, 0);
    }
    __syncthreads();

    const int fr = lane & 15;
    const int fk = (lane >> 4) * 8;
    f16x8 af[4], bf[4];
#pragma unroll
    for (int m = 0; m < 4; ++m)
      af[m] = *(const f16x8*)(As + (wm * 64 + m * 16 + fr) * 32 + fk);
#pragma unroll
    for (int n = 0; n < 4; ++n)
      bf[n] = *(const f16x8*)(Bs + (wn * 64 + n * 16 + fr) * 32 + fk);

#pragma unroll
    for (int m = 0; m < 4; ++m)
#pragma unroll
      for (int n = 0; n < 4; ++n)
        acc[m][n] = __builtin_amdgcn_mfma_f32_16x16x32_f16(af[m], bf[n], acc[m][n], 0, 0, 0);
    __syncthreads();
  }

  // epilogue: C/D layout col = lane&15, row = (lane>>4)*4 + j
  const int r4 = (lane >> 4) * 4;
  const int cc = lane & 15;
  const size_t crow0 = (size_t)tileM * 128 + wm * 64;
  const int ccol0 = tileN * 128 + wn * 64;
#pragma unroll
  for (int m = 0; m < 4; ++m)
#pragma unroll
    for (int n = 0; n < 4; ++n)
#pragma unroll
      for (int j = 0; j < 4; ++j)
        C[(crow0 + m * 16 + r4 + j) * NSTATE + ccol0 + n * 16 + cc] = (_Float16)acc[m][n][j];
}

// ---------------- per-row 1/(||k||+eps), one wave per row ----------------
__global__ __launch_bounds__(64) void rownorm_kernel(const _Float16* __restrict__ Kh,
                                                     float* __restrict__ rnorm) {
  const int r = blockIdx.x;   // 0..32767
  const f16x8* row = (const f16x8*)(Kh + (size_t)r * NSTATE);
  f16x8 v0 = row[threadIdx.x];
  f16x8 v1 = row[threadIdx.x + 64];
  float s = 0.f;
#pragma unroll
  for (int j = 0; j < 8; ++j) {
    float a = (float)v0[j], b = (float)v1[j];
    s += a * a + b * b;
  }
#pragma unroll
  for (int off = 32; off > 0; off >>= 1) s += __shfl_down(s, off);
  if (threadIdx.x == 0) rnorm[r] = 1.f / (sqrtf(s) + 1e-6f);
}

// ---------------- sequential scan over t, one channel per lane ----------------
// 64 blocks x 256 threads = 16384 channels, 4 waves/CU. Serial chain per step:
// fma -> v_exp -> add -> v_rcp -> fma (5 dependent VALU ops).
#define STILE 16
__global__ __launch_bounds__(256) void scan_kernel(const _Float16* __restrict__ K,
                                                   const _Float16* __restrict__ V,
                                                   const _Float16* __restrict__ Q,
                                                   const float* __restrict__ rn,
                                                   float* __restrict__ out,
                                                   float* __restrict__ sfin) {
  const int c = blockIdx.x * 256 + threadIdx.x;   // 0..16383
  const int b = c >> 10;
  float S = 0.f;
  _Float16 ka[STILE], va[STILE], qa[STILE];
  _Float16 kb[STILE], vb[STILE], qb[STILE];
  float ra[STILE], rb[STILE];

  auto LD = [&](_Float16* kx, _Float16* vx, _Float16* qx, float* rx, int t0) {
#pragma unroll
    for (int i = 0; i < STILE; ++i) {
      int t = t0 + i;
      t = t < T_STEPS ? t : (T_STEPS - 1);   // clamp: harmless tail loads
      size_t off = (size_t)t * NCH + c;
      kx[i] = K[off];
      vx[i] = V[off];
      qx[i] = Q[off];
      rx[i] = rn[t * BATCH + b];
    }
  };

  constexpr float L2E2 = 2.8853900817779268f;   // 2*log2(e)
  constexpr float L2E = 1.4426950408889634f;    // log2(e)

  auto STEP = [&](const _Float16* kx, const _Float16* vx, const _Float16* qx,
                  const float* rx, int t0) {
    float a2[STILE], b2[STILE], qf[STILE];
#pragma unroll
    for (int i = 0; i < STILE; ++i) {   // parallel phase (no S dependency)
      float kn = (float)kx[i] * rx[i];
      a2[i] = L2E2 * (1.f - kn * kn);
      b2[i] = L2E2 * ((float)vx[i] * kn);
      qf[i] = (float)qx[i];
    }
#pragma unroll
    for (int i = 0; i < STILE; ++i) {
      // tanh(x) = 1 - 2/(exp2(x*2log2e)+1); a2/b2 pre-scaled by 2log2e
      float u = fmaf(S, a2[i], b2[i]);
      float e = __builtin_amdgcn_exp2f(u);
      float r = __builtin_amdgcn_rcpf(e + 1.f);
      S = fmaf(-2.f, r, 1.f);
      // output (off the serial chain, ILP with next step)
      float z = S * qf[i];
      float sg = __builtin_amdgcn_rcpf(1.f + __builtin_amdgcn_exp2f(-L2E * z));
      out[(size_t)(t0 + i) * NCH + c] = z * z * sg;
    }
  };

  LD(ka, va, qa, ra, 0);
  for (int t0 = 0; t0 < T_STEPS; t0 += 2 * STILE) {
    LD(kb, vb, qb, rb, t0 + STILE);
    STEP(ka, va, qa, ra, t0);
    LD(ka, va, qa, ra, t0 + 2 * STILE);
    STEP(kb, vb, qb, rb, t0 + STILE);
  }
  sfin[c] = S;
}

extern "C" void kernel_launch(void* const* d_in, const int* in_sizes, int n_in,
                              void* d_out, int out_size, void* d_ws, size_t ws_size,
                              hipStream_t stream) {
  const float* x = (const float*)d_in[0];
  const float* Wk = (const float*)d_in[1];
  const float* Wv = (const float*)d_in[2];
  const float* Wq = (const float*)d_in[3];

  char* ws = (char*)d_ws;
  _Float16* xh = (_Float16*)ws;                               // 64 MiB
  _Float16* Wh = (_Float16*)(ws + (size_t)67108864);          // 6 MiB
  _Float16* KVQ = (_Float16*)(ws + (size_t)67108864 + 6291456); // 3*64 MiB
  _Float16* Kh = KVQ;
  _Float16* Vh = KVQ + (size_t)MROWS * NSTATE;
  _Float16* Qh = Vh + (size_t)MROWS * NSTATE;
  float* rn = (float*)(ws + (size_t)67108864 + 6291456 + 3ull * 67108864);  // 128 KiB

  int n8x = MROWS * DIMD / 8;
  cvt_kernel<<<(n8x + 255) / 256, 256, 0, stream>>>(x, xh, n8x);
  int n8w = NSTATE * DIMD / 8;
  cvt_kernel<<<(n8w + 255) / 256, 256, 0, stream>>>(Wk, Wh, n8w);
  cvt_kernel<<<(n8w + 255) / 256, 256, 0, stream>>>(Wv, Wh + (size_t)NSTATE * DIMD, n8w);
  cvt_kernel<<<(n8w + 255) / 256, 256, 0, stream>>>(Wq, Wh + (size_t)2 * NSTATE * DIMD, n8w);

  gemm_kernel<<<dim3(8, 256, 3), 256, 0, stream>>>(xh, Wh, KVQ);

  rownorm_kernel<<<MROWS, 64, 0, stream>>>(Kh, rn);

  float* outp = (float*)d_out;
  scan_kernel<<<NCH / 256, 256, 0, stream>>>(Kh, Vh, Qh, rn, outp, outp + (size_t)MROWS * NSTATE);
}

// Round 3
// 511.124 us; speedup vs baseline: 1.3389x; 1.3389x over previous
//
#include <hip/hip_runtime.h>
#include <hip/hip_fp16.h>

#define T_STEPS 2048
#define BATCH 16
#define DIMD 1024
#define NSTATE 1024
#define MROWS (T_STEPS * BATCH)   // 32768
#define NCH (BATCH * NSTATE)      // 16384

typedef _Float16 f16x8 __attribute__((ext_vector_type(8)));
typedef _Float16 f16x16 __attribute__((ext_vector_type(16)));
typedef float f32x4 __attribute__((ext_vector_type(4)));
typedef float f32x16 __attribute__((ext_vector_type(16)));

#define GAS(p) ((const __attribute__((address_space(1))) void*)(p))
#define LAS(p) ((__attribute__((address_space(3))) void*)(p))

// ---------------- f32 -> f16 convert, 8 elements/thread ----------------
__global__ void cvt_kernel(const float* __restrict__ src, _Float16* __restrict__ dst, int n8) {
  int i = blockIdx.x * blockDim.x + threadIdx.x;
  if (i >= n8) return;
  const float4* s4 = (const float4*)src;
  float4 a = s4[(size_t)i * 2];
  float4 b = s4[(size_t)i * 2 + 1];
  f16x8 o;
  o[0] = (_Float16)a.x; o[1] = (_Float16)a.y; o[2] = (_Float16)a.z; o[3] = (_Float16)a.w;
  o[4] = (_Float16)b.x; o[5] = (_Float16)b.y; o[6] = (_Float16)b.z; o[7] = (_Float16)b.w;
  *((f16x8*)dst + i) = o;
}

// ---------------- GEMM: C[m][n] = sum_d A[m][d] * W[n][d]  (NT layout), f16 out ----
__global__ void gemm_kernel(const _Float16* __restrict__ A,
                            const _Float16* __restrict__ Wcat,
                            _Float16* __restrict__ Cout) {
  __shared__ _Float16 As[128 * 32];
  __shared__ _Float16 Bs[128 * 32];
  const int tid = threadIdx.x;
  const int lane = tid & 63;
  const int wid = tid >> 6;
  const int wm = wid >> 1;   // 0..1
  const int wn = wid & 1;    // 0..1
  const int tileN = blockIdx.x;   // 0..7
  const int tileM = blockIdx.y;   // 0..255
  const int mat = blockIdx.z;     // 0..2  (k, v, q)

  const _Float16* Ag = A + (size_t)tileM * 128 * DIMD;
  const _Float16* Bg = Wcat + (size_t)mat * NSTATE * DIMD + (size_t)tileN * 128 * DIMD;
  _Float16* C = Cout + (size_t)mat * MROWS * NSTATE;

  f32x4 acc[4][4];
#pragma unroll
  for (int m = 0; m < 4; ++m)
#pragma unroll
    for (int n = 0; n < 4; ++n)
      acc[m][n] = (f32x4){0.f, 0.f, 0.f, 0.f};

  const int srow = tid >> 2;         // 0..63
  const int scolh = (tid & 3) * 8;   // offset within BK=32

  for (int kt = 0; kt < DIMD; kt += 32) {
#pragma unroll
    for (int i = 0; i < 2; ++i) {
      __builtin_amdgcn_global_load_lds(GAS(Ag + (size_t)(srow + i * 64) * DIMD + kt + scolh),
                                       LAS(As + (i * 256 + tid) * 8), 16, 0, 0);
      __builtin_amdgcn_global_load_lds(GAS(Bg + (size_t)(srow + i * 64) * DIMD + kt + scolh),
                                       LAS(Bs + (i * 256 + tid) * 8), 16, 0, 0);
    }
    __syncthreads();

    const int fr = lane & 15;
    const int fk = (lane >> 4) * 8;
    f16x8 af[4], bf[4];
#pragma unroll
    for (int m = 0; m < 4; ++m)
      af[m] = *(const f16x8*)(As + (wm * 64 + m * 16 + fr) * 32 + fk);
#pragma unroll
    for (int n = 0; n < 4; ++n)
      bf[n] = *(const f16x8*)(Bs + (wn * 64 + n * 16 + fr) * 32 + fk);

#pragma unroll
    for (int m = 0; m < 4; ++m)
#pragma unroll
      for (int n = 0; n < 4; ++n)
        acc[m][n] = __builtin_amdgcn_mfma_f32_16x16x32_f16(af[m], bf[n], acc[m][n], 0, 0, 0);
    __syncthreads();
  }

  // epilogue: C/D layout col = lane&15, row = (lane>>4)*4 + j
  const int r4 = (lane >> 4) * 4;
  const int cc = lane & 15;
  const size_t crow0 = (size_t)tileM * 128 + wm * 64;
  const int ccol0 = tileN * 128 + wn * 64;
#pragma unroll
  for (int m = 0; m < 4; ++m)
#pragma unroll
    for (int n = 0; n < 4; ++n)
#pragma unroll
      for (int j = 0; j < 4; ++j)
        C[(crow0 + m * 16 + r4 + j) * NSTATE + ccol0 + n * 16 + cc] = (_Float16)acc[m][n][j];
}

// ---------------- in-place row L2-normalize of K (one wave per row) ----------------
__global__ __launch_bounds__(64) void rownorm_kernel(_Float16* __restrict__ Kh) {
  const int r = blockIdx.x;   // 0..32767
  f16x8* row = (f16x8*)(Kh + (size_t)r * NSTATE);
  f16x8 v0 = row[threadIdx.x];
  f16x8 v1 = row[threadIdx.x + 64];
  float s = 0.f;
#pragma unroll
  for (int j = 0; j < 8; ++j) {
    float a = (float)v0[j], b = (float)v1[j];
    s += a * a + b * b;
  }
#pragma unroll
  for (int off = 32; off > 0; off >>= 1) s += __shfl_down(s, off);
  float rnorm = 1.f / (sqrtf(__shfl(s, 0)) + 1e-6f);
  f16x8 o0, o1;
#pragma unroll
  for (int j = 0; j < 8; ++j) {
    o0[j] = (_Float16)((float)v0[j] * rnorm);
    o1[j] = (_Float16)((float)v1[j] * rnorm);
  }
  row[threadIdx.x] = o0;
  row[threadIdx.x + 64] = o1;
}

// ---------------- sequential scan over t, one channel per lane ----------------
// 256 blocks x 64 threads = 1 wave/CU across all 256 CUs.
// All tile state in ext-vector REGISTERS (constant indices only, no lambdas/arrays)
// to prevent scratch spill (round-2 pathology). Depth-2 prefetch, STILE=16.
#define STILE 16

#define LOADT(P, t0)                                                         \
  do {                                                                       \
    _Pragma("unroll") for (int i = 0; i < STILE; ++i) {                      \
      int t = (t0) + i;                                                      \
      t = t < T_STEPS ? t : (T_STEPS - 1);                                   \
      size_t off = (size_t)t * NCH + c;                                      \
      P##k[i] = Kn[off];                                                     \
      P##v[i] = V[off];                                                      \
      P##q[i] = Q[off];                                                      \
    }                                                                        \
  } while (0)

#define STEPT(P, t0)                                                         \
  do {                                                                       \
    f32x16 a2, b2, qf;                                                       \
    _Pragma("unroll") for (int i = 0; i < STILE; ++i) {                      \
      float kn = (float)P##k[i];                                             \
      a2[i] = L2E2 - (L2E2 * kn) * kn;                                       \
      b2[i] = L2E2 * ((float)P##v[i] * kn);                                  \
      qf[i] = (float)P##q[i];                                                \
    }                                                                        \
    _Pragma("unroll") for (int i = 0; i < STILE; ++i) {                      \
      float u = fmaf(S, a2[i], b2[i]);                                       \
      float e = __builtin_amdgcn_exp2f(u);                                   \
      float r = __builtin_amdgcn_rcpf(e + 1.f);                              \
      S = fmaf(-2.f, r, 1.f);                                                \
      float z = S * qf[i];                                                   \
      float sg = __builtin_amdgcn_rcpf(1.f + __builtin_amdgcn_exp2f(-L2E * z)); \
      out[(size_t)((t0) + i) * NCH + c] = z * z * sg;                        \
    }                                                                        \
  } while (0)

__global__ __launch_bounds__(64) void scan_kernel(const _Float16* __restrict__ Kn,
                                                  const _Float16* __restrict__ V,
                                                  const _Float16* __restrict__ Q,
                                                  float* __restrict__ out,
                                                  float* __restrict__ sfin) {
  const int c = blockIdx.x * 64 + threadIdx.x;   // 0..16383
  constexpr float L2E2 = 2.8853900817779268f;    // 2*log2(e)
  constexpr float L2E = 1.4426950408889634f;     // log2(e)
  float S = 0.f;
  f16x16 Ak, Av, Aq;
  f16x16 Bk, Bv, Bq;

  LOADT(A, 0);
  for (int t0 = 0; t0 < T_STEPS; t0 += 2 * STILE) {
    LOADT(B, t0 + STILE);        // prefetch next tile
    STEPT(A, t0);
    LOADT(A, t0 + 2 * STILE);    // prefetch next-next (clamped at tail)
    STEPT(B, t0 + STILE);
  }
  sfin[c] = S;
}

extern "C" void kernel_launch(void* const* d_in, const int* in_sizes, int n_in,
                              void* d_out, int out_size, void* d_ws, size_t ws_size,
                              hipStream_t stream) {
  const float* x = (const float*)d_in[0];
  const float* Wk = (const float*)d_in[1];
  const float* Wv = (const float*)d_in[2];
  const float* Wq = (const float*)d_in[3];

  char* ws = (char*)d_ws;
  _Float16* xh = (_Float16*)ws;                                 // 64 MiB
  _Float16* Wh = (_Float16*)(ws + (size_t)67108864);            // 6 MiB
  _Float16* KVQ = (_Float16*)(ws + (size_t)67108864 + 6291456); // 3*64 MiB
  _Float16* Kh = KVQ;
  _Float16* Vh = KVQ + (size_t)MROWS * NSTATE;
  _Float16* Qh = Vh + (size_t)MROWS * NSTATE;

  int n8x = MROWS * DIMD / 8;
  cvt_kernel<<<(n8x + 255) / 256, 256, 0, stream>>>(x, xh, n8x);
  int n8w = NSTATE * DIMD / 8;
  cvt_kernel<<<(n8w + 255) / 256, 256, 0, stream>>>(Wk, Wh, n8w);
  cvt_kernel<<<(n8w + 255) / 256, 256, 0, stream>>>(Wv, Wh + (size_t)NSTATE * DIMD, n8w);
  cvt_kernel<<<(n8w + 255) / 256, 256, 0, stream>>>(Wq, Wh + (size_t)2 * NSTATE * DIMD, n8w);

  gemm_kernel<<<dim3(8, 256, 3), 256, 0, stream>>>(xh, Wh, KVQ);

  // in-place L2-normalize of k rows (k_norm stored as f16)
  rownorm_kernel<<<MROWS, 64, 0, stream>>>(Kh);

  float* outp = (float*)d_out;
  scan_kernel<<<NCH / 64, 64, 0, stream>>>(Kh, Vh, Qh, outp, outp + (size_t)MROWS * NSTATE);
}

// Round 4
// 434.730 us; speedup vs baseline: 1.5742x; 1.1757x over previous
//
#include <hip/hip_runtime.h>
#include <hip/hip_fp16.h>

#define T_STEPS 2048
#define BATCH 16
#define DIMD 1024
#define NSTATE 1024
#define MROWS (T_STEPS * BATCH)   // 32768
#define NCH (BATCH * NSTATE)      // 16384
#define NKT (DIMD / 32)           // 32 K-tiles

typedef _Float16 f16x8 __attribute__((ext_vector_type(8)));
typedef float f32x4 __attribute__((ext_vector_type(4)));

#define GAS(p) ((const __attribute__((address_space(1))) void*)(p))
#define LAS(p) ((__attribute__((address_space(3))) void*)(p))

// ---------------- f32 -> f16 convert, 8 elements/thread ----------------
__global__ void cvt_kernel(const float* __restrict__ src, _Float16* __restrict__ dst, int n8) {
  int i = blockIdx.x * blockDim.x + threadIdx.x;
  if (i >= n8) return;
  const float4* s4 = (const float4*)src;
  float4 a = s4[(size_t)i * 2];
  float4 b = s4[(size_t)i * 2 + 1];
  f16x8 o;
  o[0] = (_Float16)a.x; o[1] = (_Float16)a.y; o[2] = (_Float16)a.z; o[3] = (_Float16)a.w;
  o[4] = (_Float16)b.x; o[5] = (_Float16)b.y; o[6] = (_Float16)b.z; o[7] = (_Float16)b.w;
  *((f16x8*)dst + i) = o;
}

// ================= GEMM: 256x256 tile, BK=32, 8 waves, 2-phase counted-vmcnt ======
// C[m][n] = sum_d A[m][d] * W[n][d]. Output in blocked-transposed layout
// [tchunk = t>>3][c = b*1024 + n][t&7] f16, plus k^2 row partials for the norm.
__global__ __launch_bounds__(512, 2) void gemm_kernel(const _Float16* __restrict__ A,
                                                      const _Float16* __restrict__ Wcat,
                                                      _Float16* __restrict__ KVQt,
                                                      float* __restrict__ rnpart) {
  __shared__ _Float16 As[2][256 * 32];
  __shared__ _Float16 Bs[2][256 * 32];
  const int tid = threadIdx.x;
  const int lane = tid & 63;
  const int w = tid >> 6;    // 0..7
  const int wr = w >> 2;     // 0..1 : M half (128 rows)
  const int wc = w & 3;      // 0..3 : N quarter (64 cols)

  // XCD-aware bijective swizzle: 1536 blocks = 8 XCDs x 192 (tileN fastest inside)
  const int bid = blockIdx.x;
  const int swz = (bid & 7) * 192 + (bid >> 3);
  const int mat = swz >> 9;        // 0..2 (k,v,q)
  const int rem = swz & 511;
  const int tileM = rem >> 2;      // 0..127
  const int tileN = rem & 3;       // 0..3

  const _Float16* Ag = A + (size_t)tileM * 256 * DIMD;
  const _Float16* Bg = Wcat + (size_t)mat * NSTATE * DIMD + (size_t)tileN * 256 * DIMD;

  // staging: slot s = w*128 + i*64 + lane; row = s>>2; phys cb = s&3;
  // logical cb = (s&3) ^ ((s>>3)&3)  (inverse XOR swizzle applied to SOURCE)
  const int s0 = w * 128 + lane;
  const int s1 = s0 + 64;
  const int sr0 = s0 >> 2, sc0 = ((s0 & 3) ^ ((s0 >> 3) & 3)) * 8;
  const int sr1 = s1 >> 2, sc1 = ((s1 & 3) ^ ((s1 >> 3) & 3)) * 8;

#define STAGE(buf, TT)                                                                  \
  do {                                                                                  \
    const int kk = (TT) * 32;                                                           \
    __builtin_amdgcn_global_load_lds(GAS(Ag + (size_t)sr0 * DIMD + kk + sc0),           \
                                     LAS(&As[buf][s0 * 8]), 16, 0, 0);                  \
    __builtin_amdgcn_global_load_lds(GAS(Ag + (size_t)sr1 * DIMD + kk + sc1),           \
                                     LAS(&As[buf][s1 * 8]), 16, 0, 0);                  \
    __builtin_amdgcn_global_load_lds(GAS(Bg + (size_t)sr0 * DIMD + kk + sc0),           \
                                     LAS(&Bs[buf][s0 * 8]), 16, 0, 0);                  \
    __builtin_amdgcn_global_load_lds(GAS(Bg + (size_t)sr1 * DIMD + kk + sc1),           \
                                     LAS(&Bs[buf][s1 * 8]), 16, 0, 0);                  \
  } while (0)

  f32x4 acc[8][4];
#pragma unroll
  for (int m = 0; m < 8; ++m)
#pragma unroll
    for (int n = 0; n < 4; ++n)
      acc[m][n] = (f32x4){0.f, 0.f, 0.f, 0.f};

  // prologue: tiles 0 and 1
  STAGE(0, 0);
  STAGE(1, 1);

  const int fr = lane & 15;
  const int cbp = ((lane >> 4) ^ ((fr >> 1) & 3)) * 8;  // phys cb element offset

#pragma unroll 2
  for (int T = 0; T < NKT; ++T) {
    const int buf = T & 1;
    // ---- tile-start sync: current tile fully in LDS, next tile may be in flight ----
    __builtin_amdgcn_sched_barrier(0);
    if (T < NKT - 2) {
      asm volatile("s_waitcnt vmcnt(4)" ::: "memory");
    } else {
      asm volatile("s_waitcnt vmcnt(0)" ::: "memory");
    }
    __builtin_amdgcn_s_barrier();
    __builtin_amdgcn_sched_barrier(0);

    // ---- P1: all LDS reads for this tile + MFMA quadrant n={0,1} ----
    f16x8 af[8], bf[4];
#pragma unroll
    for (int m = 0; m < 8; ++m)
      af[m] = *(const f16x8*)(&As[buf][(wr * 128 + m * 16 + fr) * 32 + cbp]);
#pragma unroll
    for (int n = 0; n < 4; ++n)
      bf[n] = *(const f16x8*)(&Bs[buf][(wc * 64 + n * 16 + fr) * 32 + cbp]);

    __builtin_amdgcn_s_setprio(1);
#pragma unroll
    for (int m = 0; m < 8; ++m)
#pragma unroll
      for (int n = 0; n < 2; ++n)
        acc[m][n] = __builtin_amdgcn_mfma_f32_16x16x32_f16(af[m], bf[n], acc[m][n], 0, 0, 0);
    __builtin_amdgcn_s_setprio(0);

    // all reads of this tile complete before the write phase
    asm volatile("s_waitcnt lgkmcnt(0)" ::: "memory");
    __builtin_amdgcn_sched_barrier(0);
    __builtin_amdgcn_s_barrier();
    __builtin_amdgcn_sched_barrier(0);

    // ---- P2: stage tile T+2 into this buffer + MFMA quadrant n={2,3} ----
    if (T < NKT - 2) STAGE(buf, T + 2);
    __builtin_amdgcn_s_setprio(1);
#pragma unroll
    for (int m = 0; m < 8; ++m)
#pragma unroll
      for (int n = 2; n < 4; ++n)
        acc[m][n] = __builtin_amdgcn_mfma_f32_16x16x32_f16(af[m], bf[n], acc[m][n], 0, 0, 0);
    __builtin_amdgcn_s_setprio(0);
  }

  // ---- epilogue: blocked-transposed store [tchunk][c][8] ----
  // C/D: col = lane&15, row16 = (lane>>4)*4 + j ; global row = tileM*256+wr*128+m*16+row16
  // => t = tileM*16 + wr*8 + m (chunk-aligned!), b = row16
  const int cc = lane & 15;
  const int l4 = lane >> 4;
  _Float16* Cb = KVQt + (size_t)mat * ((size_t)MROWS * NSTATE) +
                 (size_t)(tileM * 2 + wr) * ((size_t)NCH * 8);
#pragma unroll
  for (int n = 0; n < 4; ++n)
#pragma unroll
    for (int j = 0; j < 4; ++j) {
      f16x8 pk;
#pragma unroll
      for (int m = 0; m < 8; ++m) pk[m] = (_Float16)acc[m][n][j];
      const int b = l4 * 4 + j;
      const int gcol = tileN * 256 + wc * 64 + n * 16 + cc;
      *(f16x8*)(Cb + ((size_t)(b * 1024 + gcol)) * 8) = pk;
    }

  // ---- k^2 row partials (mat 0 only), deterministic per-(tileN,wc) slot ----
  if (mat == 0) {
#pragma unroll
    for (int m = 0; m < 8; ++m)
#pragma unroll
      for (int j = 0; j < 4; ++j) {
        float p = 0.f;
#pragma unroll
        for (int n = 0; n < 4; ++n) p += acc[m][n][j] * acc[m][n][j];
        p += __shfl_xor(p, 1);
        p += __shfl_xor(p, 2);
        p += __shfl_xor(p, 4);
        p += __shfl_xor(p, 8);
        if (cc == 0) {
          const int gr = tileM * 256 + wr * 128 + m * 16 + l4 * 4 + j;
          rnpart[(size_t)(tileN * 4 + wc) * MROWS + gr] = p;
        }
      }
  }
}

// ---------------- finalize: rn[r] = 1/(||k_row|| + eps) ----------------
__global__ void rnfin_kernel(const float* __restrict__ part, float* __restrict__ rn) {
  const int r = blockIdx.x * 256 + threadIdx.x;
  float s = 0.f;
#pragma unroll
  for (int i = 0; i < 16; ++i) s += part[(size_t)i * MROWS + r];
  rn[r] = 1.f / (sqrtf(s) + 1e-6f);
}

// ---------------- sequential scan, blocked layout [t>>3][c][t&7] ----------------
#define STILE 16

#define LOADT(P, t0in)                                                        \
  do {                                                                        \
    const int tc = ((t0in) < T_STEPS) ? (t0in) : (T_STEPS - STILE);           \
    const size_t o0 = ((size_t)(tc >> 3) * NCH + c) * 8;                      \
    P##k0 = *(const f16x8*)(Kt + o0);                                         \
    P##k1 = *(const f16x8*)(Kt + o0 + (size_t)NCH * 8);                       \
    P##v0 = *(const f16x8*)(Vt + o0);                                         \
    P##v1 = *(const f16x8*)(Vt + o0 + (size_t)NCH * 8);                       \
    P##q0 = *(const f16x8*)(Qt + o0);                                         \
    P##q1 = *(const f16x8*)(Qt + o0 + (size_t)NCH * 8);                       \
    _Pragma("unroll") for (int i = 0; i < STILE; ++i)                         \
        P##r[i] = rn[(tc + i) * 16 + b];                                      \
  } while (0)

#define STEPT(P, t0)                                                          \
  do {                                                                        \
    float a2[STILE], b2[STILE], qf[STILE];                                    \
    _Pragma("unroll") for (int i = 0; i < STILE; ++i) {                       \
      float kf = (float)((i < 8) ? P##k0[i & 7] : P##k1[i & 7]);              \
      float vf = (float)((i < 8) ? P##v0[i & 7] : P##v1[i & 7]);              \
      float kn = kf * P##r[i];                                                \
      a2[i] = L2E2 - (L2E2 * kn) * kn;                                        \
      b2[i] = L2E2 * (vf * kn);                                               \
      qf[i] = (float)((i < 8) ? P##q0[i & 7] : P##q1[i & 7]);                 \
    }                                                                         \
    _Pragma("unroll") for (int i = 0; i < STILE; ++i) {                       \
      float u = fmaf(S, a2[i], b2[i]);                                        \
      float e = __builtin_amdgcn_exp2f(u);                                    \
      float r = __builtin_amdgcn_rcpf(e + 1.f);                               \
      S = fmaf(-2.f, r, 1.f);                                                 \
      float z = S * qf[i];                                                    \
      float sg = __builtin_amdgcn_rcpf(1.f + __builtin_amdgcn_exp2f(-L2E * z)); \
      out[(size_t)((t0) + i) * NCH + c] = z * z * sg;                         \
    }                                                                         \
  } while (0)

__global__ __launch_bounds__(256) void scan_kernel(const _Float16* __restrict__ Kt,
                                                   const _Float16* __restrict__ Vt,
                                                   const _Float16* __restrict__ Qt,
                                                   const float* __restrict__ rn,
                                                   float* __restrict__ out,
                                                   float* __restrict__ sfin) {
  const int c = blockIdx.x * 256 + threadIdx.x;   // 0..16383
  const int b = c >> 10;                          // uniform per block
  constexpr float L2E2 = 2.8853900817779268f;     // 2*log2(e)
  constexpr float L2E = 1.4426950408889634f;      // log2(e)
  float S = 0.f;
  f16x8 Ak0, Ak1, Av0, Av1, Aq0, Aq1;
  f16x8 Bk0, Bk1, Bv0, Bv1, Bq0, Bq1;
  float Ar[STILE], Br[STILE];

  LOADT(A, 0);
  for (int t0 = 0; t0 < T_STEPS; t0 += 2 * STILE) {
    LOADT(B, t0 + STILE);
    STEPT(A, t0);
    LOADT(A, t0 + 2 * STILE);
    STEPT(B, t0 + STILE);
  }
  sfin[c] = S;
}

extern "C" void kernel_launch(void* const* d_in, const int* in_sizes, int n_in,
                              void* d_out, int out_size, void* d_ws, size_t ws_size,
                              hipStream_t stream) {
  const float* x = (const float*)d_in[0];
  const float* Wk = (const float*)d_in[1];
  const float* Wv = (const float*)d_in[2];
  const float* Wq = (const float*)d_in[3];

  char* ws = (char*)d_ws;
  _Float16* xh = (_Float16*)ws;                                   // 64 MiB
  _Float16* Wh = (_Float16*)(ws + 67108864ull);                   // 6 MiB
  _Float16* KVQt = (_Float16*)(ws + 67108864ull + 6291456ull);    // 192 MiB
  float* rnpart = (float*)(ws + 67108864ull + 6291456ull + 201326592ull);  // 2 MiB
  float* rn = (float*)(ws + 67108864ull + 6291456ull + 201326592ull + 2097152ull);  // 128 KiB

  int n8x = MROWS * DIMD / 8;
  cvt_kernel<<<(n8x + 255) / 256, 256, 0, stream>>>(x, xh, n8x);
  int n8w = NSTATE * DIMD / 8;
  cvt_kernel<<<(n8w + 255) / 256, 256, 0, stream>>>(Wk, Wh, n8w);
  cvt_kernel<<<(n8w + 255) / 256, 256, 0, stream>>>(Wv, Wh + (size_t)NSTATE * DIMD, n8w);
  cvt_kernel<<<(n8w + 255) / 256, 256, 0, stream>>>(Wq, Wh + (size_t)2 * NSTATE * DIMD, n8w);

  gemm_kernel<<<1536, 512, 0, stream>>>(xh, Wh, KVQt, rnpart);

  rnfin_kernel<<<MROWS / 256, 256, 0, stream>>>(rnpart, rn);

  const _Float16* Kt = KVQt;
  const _Float16* Vt = KVQt + (size_t)MROWS * NSTATE;
  const _Float16* Qt = KVQt + 2ull * MROWS * NSTATE;
  float* outp = (float*)d_out;
  scan_kernel<<<NCH / 256, 256, 0, stream>>>(Kt, Vt, Qt, rn, outp, outp + (size_t)MROWS * NSTATE);
}

// Round 5
// 424.737 us; speedup vs baseline: 1.6112x; 1.0235x over previous
//
#include <hip/hip_runtime.h>
#include <hip/hip_fp16.h>

#define T_STEPS 2048
#define BATCH 16
#define DIMD 1024
#define NSTATE 1024
#define MROWS (T_STEPS * BATCH)   // 32768
#define NCH (BATCH * NSTATE)      // 16384
#define NKT (DIMD / 32)           // 32 K-tiles

typedef _Float16 f16x4 __attribute__((ext_vector_type(4)));
typedef _Float16 f16x8 __attribute__((ext_vector_type(8)));
typedef float f32x4 __attribute__((ext_vector_type(4)));

#define GAS(p) ((const __attribute__((address_space(1))) void*)(p))
#define LAS(p) ((__attribute__((address_space(3))) void*)(p))

// ---------------- f32 -> f16 convert, 8 elements/thread ----------------
__global__ void cvt_kernel(const float* __restrict__ src, _Float16* __restrict__ dst, int n8) {
  int i = blockIdx.x * blockDim.x + threadIdx.x;
  if (i >= n8) return;
  const float4* s4 = (const float4*)src;
  float4 a = s4[(size_t)i * 2];
  float4 b = s4[(size_t)i * 2 + 1];
  f16x8 o;
  o[0] = (_Float16)a.x; o[1] = (_Float16)a.y; o[2] = (_Float16)a.z; o[3] = (_Float16)a.w;
  o[4] = (_Float16)b.x; o[5] = (_Float16)b.y; o[6] = (_Float16)b.z; o[7] = (_Float16)b.w;
  *((f16x8*)dst + i) = o;
}

// ================= GEMM: 128x256 tile, BK=32, 4 waves, 3-buf 1-barrier ======
// C[m][n] = sum_d A[m][d] * W[n][d]. Output blocked-transposed [t>>3][c][t&7] f16,
// plus k^2 row partials. Triple-buffered LDS: stage tile j+2 issued right after the
// tile-j barrier (buffer freed by tile j-1); counted vmcnt(6), never 0 in main loop.
#define A_ELEMS (128 * 32)
#define B_ELEMS (256 * 32)
__global__ __launch_bounds__(256, 2) void gemm_kernel(const _Float16* __restrict__ A,
                                                      const _Float16* __restrict__ Wcat,
                                                      _Float16* __restrict__ KVQt,
                                                      float* __restrict__ rnpart) {
  __shared__ _Float16 As[3][A_ELEMS];
  __shared__ _Float16 Bs[3][B_ELEMS];
  const int tid = threadIdx.x;
  const int lane = tid & 63;
  const int w = tid >> 6;    // 0..3
  const int wr = w >> 1;     // 0..1 : M half (64 rows)
  const int wc = w & 1;      // 0..1 : N half (128 cols)

  // XCD-aware bijective swizzle: 3072 blocks = 8 XCDs x 384 (tileN fastest inside)
  const int bid = blockIdx.x;
  const int swz = (bid & 7) * 384 + (bid >> 3);
  const int mat = swz >> 10;       // 0..2 (k,v,q)
  const int rem = swz & 1023;
  const int tileM = rem >> 2;      // 0..255
  const int tileN = rem & 3;       // 0..3

  const _Float16* Ag = A + (size_t)tileM * 128 * DIMD;
  const _Float16* Bg = Wcat + (size_t)mat * NSTATE * DIMD + (size_t)tileN * 256 * DIMD;

  // staging slot s: row = s>>2, phys cb = s&3, logical cb = (s&3)^((s>>3)&3)
  // (inverse XOR swizzle applied to the SOURCE address; LDS dest stays linear)
#define STAGE(buf, TT)                                                                   \
  do {                                                                                   \
    const int kk = (TT) * 32;                                                            \
    _Pragma("unroll") for (int i = 0; i < 2; ++i) {                                      \
      const int s = i * 256 + tid;                                                       \
      const int sr = s >> 2, sc = ((s & 3) ^ ((s >> 3) & 3)) * 8;                        \
      __builtin_amdgcn_global_load_lds(GAS(Ag + (size_t)sr * DIMD + kk + sc),            \
                                       LAS(&As[buf][s * 8]), 16, 0, 0);                  \
    }                                                                                    \
    _Pragma("unroll") for (int i = 0; i < 4; ++i) {                                      \
      const int s = i * 256 + tid;                                                       \
      const int sr = s >> 2, sc = ((s & 3) ^ ((s >> 3) & 3)) * 8;                        \
      __builtin_amdgcn_global_load_lds(GAS(Bg + (size_t)sr * DIMD + kk + sc),            \
                                       LAS(&Bs[buf][s * 8]), 16, 0, 0);                  \
    }                                                                                    \
  } while (0)

  f32x4 acc[4][8];
#pragma unroll
  for (int m = 0; m < 4; ++m)
#pragma unroll
    for (int n = 0; n < 8; ++n)
      acc[m][n] = (f32x4){0.f, 0.f, 0.f, 0.f};

  // prologue: tiles 0 and 1
  STAGE(0, 0);
  STAGE(1, 1);

  const int fr = lane & 15;
  const int cbp = ((lane >> 4) ^ ((fr >> 1) & 3)) * 8;  // phys cb element offset

#pragma unroll
  for (int T = 0; T < NKT; ++T) {
    const int buf = T % 3;
    // tile T fully landed (tile T+1's 6 loads may remain in flight)
    if (T < NKT - 1) {
      asm volatile("s_waitcnt vmcnt(6)" ::: "memory");
    } else {
      asm volatile("s_waitcnt vmcnt(0)" ::: "memory");
    }
    __builtin_amdgcn_s_barrier();          // raw: no forced drain
    __builtin_amdgcn_sched_barrier(0);

    // stage tile T+2 into the buffer freed by tile T-1 (reads retired pre-barrier)
    if (T < NKT - 2) STAGE((T + 2) % 3, T + 2);

    f16x8 af[4], bf[8];
#pragma unroll
    for (int m = 0; m < 4; ++m)
      af[m] = *(const f16x8*)(&As[buf][(wr * 64 + m * 16 + fr) * 32 + cbp]);
#pragma unroll
    for (int n = 0; n < 8; ++n)
      bf[n] = *(const f16x8*)(&Bs[buf][(wc * 128 + n * 16 + fr) * 32 + cbp]);

    __builtin_amdgcn_s_setprio(1);
#pragma unroll
    for (int m = 0; m < 4; ++m)
#pragma unroll
      for (int n = 0; n < 8; ++n)
        acc[m][n] = __builtin_amdgcn_mfma_f32_16x16x32_f16(af[m], bf[n], acc[m][n], 0, 0, 0);
    __builtin_amdgcn_s_setprio(0);
  }

  // ---- epilogue: blocked-transposed store [tchunk][c][8] ----
  // global row r = tileM*128 + wr*64 + m*16 + (lane>>4)*4 + j ; r = t*16 + b
  // => tchunk = tileM, within-chunk t&7 = wr*4 + m, b = (lane>>4)*4 + j
  const int cc = lane & 15;
  const int l4 = lane >> 4;
  _Float16* Cb = KVQt + (size_t)mat * ((size_t)MROWS * NSTATE) +
                 (size_t)tileM * ((size_t)NCH * 8);
#pragma unroll
  for (int n = 0; n < 8; ++n)
#pragma unroll
    for (int j = 0; j < 4; ++j) {
      f16x4 pk;
#pragma unroll
      for (int m = 0; m < 4; ++m) pk[m] = (_Float16)acc[m][n][j];
      const int b = l4 * 4 + j;
      const int gcol = tileN * 256 + wc * 128 + n * 16 + cc;
      *(f16x4*)(Cb + ((size_t)(b * 1024 + gcol)) * 8 + wr * 4) = pk;
    }

  // ---- k^2 row partials (mat 0 only), slot = tileN*2 + wc (deterministic) ----
  if (mat == 0) {
#pragma unroll
    for (int m = 0; m < 4; ++m)
#pragma unroll
      for (int j = 0; j < 4; ++j) {
        float p = 0.f;
#pragma unroll
        for (int n = 0; n < 8; ++n) p += acc[m][n][j] * acc[m][n][j];
        p += __shfl_xor(p, 1);
        p += __shfl_xor(p, 2);
        p += __shfl_xor(p, 4);
        p += __shfl_xor(p, 8);
        if (cc == 0) {
          const int gr = tileM * 128 + wr * 64 + m * 16 + l4 * 4 + j;
          rnpart[(size_t)(tileN * 2 + wc) * MROWS + gr] = p;
        }
      }
  }
}

// ---------------- finalize: rn[r] = 1/(||k_row|| + eps) ----------------
__global__ void rnfin_kernel(const float* __restrict__ part, float* __restrict__ rn) {
  const int r = blockIdx.x * 256 + threadIdx.x;
  float s = 0.f;
#pragma unroll
  for (int i = 0; i < 8; ++i) s += part[(size_t)i * MROWS + r];
  rn[r] = 1.f / (sqrtf(s) + 1e-6f);
}

// ---------------- sequential scan, blocked layout [t>>3][c][t&7] ----------------
// 256 blocks x 64 threads = 1 wave per CU on all 256 CUs (VALU-issue-bound kernel).
#define STILE 16

#define LOADT(P, t0in)                                                        \
  do {                                                                        \
    const int tc = ((t0in) < T_STEPS) ? (t0in) : (T_STEPS - STILE);           \
    const size_t o0 = ((size_t)(tc >> 3) * NCH + c) * 8;                      \
    P##k0 = *(const f16x8*)(Kt + o0);                                         \
    P##k1 = *(const f16x8*)(Kt + o0 + (size_t)NCH * 8);                       \
    P##v0 = *(const f16x8*)(Vt + o0);                                         \
    P##v1 = *(const f16x8*)(Vt + o0 + (size_t)NCH * 8);                       \
    P##q0 = *(const f16x8*)(Qt + o0);                                         \
    P##q1 = *(const f16x8*)(Qt + o0 + (size_t)NCH * 8);                       \
    _Pragma("unroll") for (int i = 0; i < STILE; ++i)                         \
        P##r[i] = rn[(tc + i) * 16 + b];                                      \
  } while (0)

#define STEPT(P, t0)                                                          \
  do {                                                                        \
    float a2[STILE], b2[STILE], qf[STILE];                                    \
    _Pragma("unroll") for (int i = 0; i < STILE; ++i) {                       \
      float kf = (float)((i < 8) ? P##k0[i & 7] : P##k1[i & 7]);              \
      float vf = (float)((i < 8) ? P##v0[i & 7] : P##v1[i & 7]);              \
      float kn = kf * P##r[i];                                                \
      a2[i] = L2E2 - (L2E2 * kn) * kn;                                        \
      b2[i] = L2E2 * (vf * kn);                                               \
      qf[i] = (float)((i < 8) ? P##q0[i & 7] : P##q1[i & 7]);                 \
    }                                                                         \
    _Pragma("unroll") for (int i = 0; i < STILE; ++i) {                       \
      float u = fmaf(S, a2[i], b2[i]);                                        \
      float e = __builtin_amdgcn_exp2f(u);                                    \
      float r = __builtin_amdgcn_rcpf(e + 1.f);                               \
      S = fmaf(-2.f, r, 1.f);                                                 \
      float z = S * qf[i];                                                    \
      float sg = __builtin_amdgcn_rcpf(1.f + __builtin_amdgcn_exp2f(-L2E * z)); \
      out[(size_t)((t0) + i) * NCH + c] = z * z * sg;                         \
    }                                                                         \
  } while (0)

__global__ __launch_bounds__(64) void scan_kernel(const _Float16* __restrict__ Kt,
                                                  const _Float16* __restrict__ Vt,
                                                  const _Float16* __restrict__ Qt,
                                                  const float* __restrict__ rn,
                                                  float* __restrict__ out,
                                                  float* __restrict__ sfin) {
  const int c = blockIdx.x * 64 + threadIdx.x;   // 0..16383
  const int b = c >> 10;                         // uniform per 64-thread block
  constexpr float L2E2 = 2.8853900817779268f;    // 2*log2(e)
  constexpr float L2E = 1.4426950408889634f;     // log2(e)
  float S = 0.f;
  f16x8 Ak0, Ak1, Av0, Av1, Aq0, Aq1;
  f16x8 Bk0, Bk1, Bv0, Bv1, Bq0, Bq1;
  float Ar[STILE], Br[STILE];

  LOADT(A, 0);
  for (int t0 = 0; t0 < T_STEPS; t0 += 2 * STILE) {
    LOADT(B, t0 + STILE);
    STEPT(A, t0);
    LOADT(A, t0 + 2 * STILE);
    STEPT(B, t0 + STILE);
  }
  sfin[c] = S;
}

extern "C" void kernel_launch(void* const* d_in, const int* in_sizes, int n_in,
                              void* d_out, int out_size, void* d_ws, size_t ws_size,
                              hipStream_t stream) {
  const float* x = (const float*)d_in[0];
  const float* Wk = (const float*)d_in[1];
  const float* Wv = (const float*)d_in[2];
  const float* Wq = (const float*)d_in[3];

  char* ws = (char*)d_ws;
  _Float16* xh = (_Float16*)ws;                                   // 64 MiB
  _Float16* Wh = (_Float16*)(ws + 67108864ull);                   // 6 MiB
  _Float16* KVQt = (_Float16*)(ws + 67108864ull + 6291456ull);    // 192 MiB
  float* rnpart = (float*)(ws + 67108864ull + 6291456ull + 201326592ull);  // 1 MiB
  float* rn = (float*)(ws + 67108864ull + 6291456ull + 201326592ull + 2097152ull);  // 128 KiB

  int n8x = MROWS * DIMD / 8;
  cvt_kernel<<<(n8x + 255) / 256, 256, 0, stream>>>(x, xh, n8x);
  int n8w = NSTATE * DIMD / 8;
  cvt_kernel<<<(n8w + 255) / 256, 256, 0, stream>>>(Wk, Wh, n8w);
  cvt_kernel<<<(n8w + 255) / 256, 256, 0, stream>>>(Wv, Wh + (size_t)NSTATE * DIMD, n8w);
  cvt_kernel<<<(n8w + 255) / 256, 256, 0, stream>>>(Wq, Wh + (size_t)2 * NSTATE * DIMD, n8w);

  gemm_kernel<<<3072, 256, 0, stream>>>(xh, Wh, KVQt, rnpart);

  rnfin_kernel<<<MROWS / 256, 256, 0, stream>>>(rnpart, rn);

  const _Float16* Kt = KVQt;
  const _Float16* Vt = KVQt + (size_t)MROWS * NSTATE;
  const _Float16* Qt = KVQt + 2ull * MROWS * NSTATE;
  float* outp = (float*)d_out;
  scan_kernel<<<NCH / 64, 64, 0, stream>>>(Kt, Vt, Qt, rn, outp, outp + (size_t)MROWS * NSTATE);
}